// Round 6
// baseline (333.620 us; speedup 1.0000x reference)
//
#include <hip/hip_runtime.h>
#include <hip/hip_bf16.h>
#include <cstdint>
#include <cstddef>

// ---------------------------------------------------------------------------
// E3nnMLPNorm: only the l=1 (d=3) irrep path is nonzero.
// layer0 (K=2) -> [gemm(+fused colsumsq) -> bn+gate] x5 -> final dot
// Precision: bf16 hi+lo pairs, 3 bf16 MFMA per fragment into f32 acc.
// GEMM R6: 64x64 tile, grid 48x16 = 768 blocks = 3 independent blocks/CU
// (m97 regime: independent barriers per block hide latency — R5 showed
// intra-block K-groups behind a shared s_barrier are NOT independent).
// 2-phase dbuf, counted vmcnt(4). Staging: each wave loads 16 rows x 64 B
// (16 line-requests/instr, 4x fewer than row-per-lane). No XCD swizzle
// (R5: it thrashed L2, FETCH 22.6->51 MB).
// ---------------------------------------------------------------------------

typedef short    s16x8 __attribute__((ext_vector_type(8)));
typedef float    f32x4 __attribute__((ext_vector_type(4)));

#define PLANE 1048576   // 1024*1024 elements per plane

__device__ __forceinline__ unsigned short f2bf(float f) {
  unsigned u = __builtin_bit_cast(unsigned, f);
  u += 0x7FFFu + ((u >> 16) & 1u);              // round-to-nearest-even
  return (unsigned short)(u >> 16);
}
__device__ __forceinline__ float bf2f(unsigned short h) {
  return __builtin_bit_cast(float, (unsigned)h << 16);
}

__device__ __forceinline__ void load_lds16(const void* g, void* l) {
  __builtin_amdgcn_global_load_lds(
      (const __attribute__((address_space(1))) unsigned int*)g,
      (__attribute__((address_space(3))) unsigned int*)l,
      16, 0, 0);
}

// ---- W[b,0] (f32 [u][v]) -> bf16 hi/lo [v][u] with 1/32 folded in ----------
__global__ void convert_w(const float* __restrict__ W,
                          unsigned short* __restrict__ Wh,
                          unsigned short* __restrict__ Wl) {
  __shared__ float t[64][65];
  const int u0 = blockIdx.x * 64, v0 = blockIdx.y * 64;
  const float* Wb = W + (size_t)blockIdx.z * 4194304;   // [5][4][1024][1024], irrep 0
  unsigned short* Whb = Wh + (size_t)blockIdx.z * PLANE;
  unsigned short* Wlb = Wl + (size_t)blockIdx.z * PLANE;
  const int c = threadIdx.x & 63, r4 = threadIdx.x >> 6;
#pragma unroll
  for (int i = 0; i < 16; ++i) {
    const int r = i * 4 + r4;
    t[r][c] = Wb[(size_t)(u0 + r) * 1024 + v0 + c];
  }
  __syncthreads();
#pragma unroll
  for (int i = 0; i < 16; ++i) {
    const int r = i * 4 + r4;   // local v index
    const float w = t[c][r] * 0.03125f;      // exact pow2 scale
    const unsigned short hi = f2bf(w);
    const size_t idx = (size_t)(v0 + r) * 1024 + u0 + c;
    Whb[idx] = hi;
    Wlb[idx] = f2bf(w - bf2f(hi));
  }
}

// ---- layer0: pre[i][b][v] = (x[b,0,i]*w1[0,v] + x[b,1,i]*w1[1,v]) / sqrt(2) -
__global__ void layer0(const float* __restrict__ x, const float* __restrict__ w1,
                       float* __restrict__ pre) {
  const int gid = blockIdx.x * 256 + threadIdx.x;   // b*1024 + v
  const int v = gid & 1023, b = gid >> 10;
  const float a0 = w1[v], a1 = w1[1024 + v];
  const float* xb = x + b * 6;                      // x flat [B][2][3]
  const float inv = 0.70710678118654752f;
#pragma unroll
  for (int i = 0; i < 3; ++i)
    pre[(size_t)i * PLANE + gid] = (xb[i] * a0 + xb[3 + i] * a1) * inv;
}

// ---- column sum of squares (layer0 only) -> var[v] (atomic) -----------------
__global__ void colsumsq(const float* __restrict__ pre, float* __restrict__ var) {
  const int col = blockIdx.y * 256 + threadIdx.x;
  const int r0 = blockIdx.x * 128;                  // 24 row-chunks of 128
  float s = 0.f;
#pragma unroll 4
  for (int r = 0; r < 128; ++r) {
    const float v = pre[(size_t)(r0 + r) * 1024 + col];
    s += v * v;
  }
  atomicAdd(&var[col], s);
}

// ---- batchnorm scale + norm-gated sigmoid, write bf16 hi/lo (x4 vector) -----
__global__ void act_kernel(const float* __restrict__ pre, const float* __restrict__ var,
                           const float* __restrict__ bnw,
                           unsigned short* __restrict__ ah,
                           unsigned short* __restrict__ al) {
  const int idx = (blockIdx.x * 256 + threadIdx.x) * 4;   // 262144 threads x4
  const int v = idx & 1023;
  const float4 p0 = *(const float4*)&pre[idx];
  const float4 p1 = *(const float4*)&pre[idx + PLANE];
  const float4 p2 = *(const float4*)&pre[idx + 2 * PLANE];
  const float a0[4] = {p0.x, p0.y, p0.z, p0.w};
  const float a1[4] = {p1.x, p1.y, p1.z, p1.w};
  const float a2[4] = {p2.x, p2.y, p2.z, p2.w};
  unsigned short H0[4], L0[4], H1[4], L1[4], H2[4], L2[4];
#pragma unroll
  for (int j = 0; j < 4; ++j) {
    const float s = bnw[v + j] / sqrtf(var[v + j] * (1.0f / 3072.0f) + 1e-5f);
    const float f0 = a0[j] * s, f1 = a1[j] * s, f2 = a2[j] * s;
    const float n = sqrtf(f0 * f0 + f1 * f1 + f2 * f2 + 1e-8f);
    const float g = 1.0f / ((1.0f + expf(-n)) * n);   // sigmoid(n)/n
    const float o0 = f0 * g, o1 = f1 * g, o2 = f2 * g;
    H0[j] = f2bf(o0); L0[j] = f2bf(o0 - bf2f(H0[j]));
    H1[j] = f2bf(o1); L1[j] = f2bf(o1 - bf2f(H1[j]));
    H2[j] = f2bf(o2); L2[j] = f2bf(o2 - bf2f(H2[j]));
  }
  *(ushort4*)&ah[idx]             = make_ushort4(H0[0], H0[1], H0[2], H0[3]);
  *(ushort4*)&al[idx]             = make_ushort4(L0[0], L0[1], L0[2], L0[3]);
  *(ushort4*)&ah[idx + PLANE]     = make_ushort4(H1[0], H1[1], H1[2], H1[3]);
  *(ushort4*)&al[idx + PLANE]     = make_ushort4(L1[0], L1[1], L1[2], L1[3]);
  *(ushort4*)&ah[idx + 2 * PLANE] = make_ushort4(H2[0], H2[1], H2[2], H2[3]);
  *(ushort4*)&al[idx + 2 * PLANE] = make_ushort4(L2[0], L2[1], L2[2], L2[3]);
}

// ---- bf16-pair MFMA GEMM + fused column-sumsq, 64x64 tile -------------------
// C[3072][1024] = (Ah+Al) * (Bh+Bl)^T ; var[col] += sum_rows C^2
// 4 waves, each wave one 32x32 quadrant (2x2 frags of 16x16x32).
// LDS per mat: [rowhi 4][kc 4][rowlo 16][8 halves] = 4 KB; wave w stages
// rows [w*16, w*16+16) x 64 B, linear in lane order (lane = kc*16 + rowlo).
__global__ __launch_bounds__(256, 3) void gemm_fused(
    const unsigned short* __restrict__ Ah, const unsigned short* __restrict__ Al,
    const unsigned short* __restrict__ Bh, const unsigned short* __restrict__ Bl,
    float* __restrict__ C, float* __restrict__ var) {
  // [buf][mat: aH,aL,bH,bL][rowhi][kc][rowlo][8 halves] = 32 KB
  __shared__ unsigned short lds[2][4][4][4][16][8];
  const int tid = threadIdx.x;
  const int bm0 = blockIdx.x * 64, bn0 = blockIdx.y * 64;
  const int lane = tid & 63, wave = tid >> 6;
  const int wm = (wave >> 1) * 32, wn = (wave & 1) * 32;
  const int rsel = lane & 15, kcsel = lane >> 4;

  f32x4 acc[2][2] = {};

  // staging: wave w covers rows [w*16, w*16+16); lane = kchunk*16 + rowlo
  // global addr = (row)*2048 + kchunk*16 (+ t*64) -> 16 line-reqs per instr
  const size_t stoff = ((size_t)(wave * 16 + rsel) << 11) + (kcsel << 4);
  const char* g0 = (const char*)Ah + ((size_t)bm0 << 11) + stoff;
  const char* g1 = (const char*)Al + ((size_t)bm0 << 11) + stoff;
  const char* g2 = (const char*)Bh + ((size_t)bn0 << 11) + stoff;
  const char* g3 = (const char*)Bl + ((size_t)bn0 << 11) + stoff;

  auto stage = [&](int buf, int t) {
    const int kb = t << 6;                           // byte offset along K
    char* base = (char*)lds + (buf << 14) + (wave << 10);  // wave-uniform
    load_lds16(g0 + kb, base);
    load_lds16(g1 + kb, base + 4096);
    load_lds16(g2 + kb, base + 8192);
    load_lds16(g3 + kb, base + 12288);
  };

  // fragment base offsets: mat*4096 + (rowhi)*1024 + kcsel*256 + rsel*16
  const int fo = kcsel * 256 + rsel * 16;
  auto compute = [&](int buf) {
    const char* p = (const char*)lds + (buf << 14);
    s16x8 fah[2], fal[2], fbh[2], fbl[2];
#pragma unroll
    for (int m = 0; m < 2; ++m) {
      fah[m] = *(const s16x8*)(p         + ((wm >> 4) + m) * 1024 + fo);
      fal[m] = *(const s16x8*)(p + 4096  + ((wm >> 4) + m) * 1024 + fo);
    }
#pragma unroll
    for (int n = 0; n < 2; ++n) {
      fbh[n] = *(const s16x8*)(p + 8192  + ((wn >> 4) + n) * 1024 + fo);
      fbl[n] = *(const s16x8*)(p + 12288 + ((wn >> 4) + n) * 1024 + fo);
    }
#pragma unroll
    for (int m = 0; m < 2; ++m)
#pragma unroll
      for (int n = 0; n < 2; ++n) {
        acc[m][n] = __builtin_amdgcn_mfma_f32_16x16x32_bf16(fal[m], fbh[n], acc[m][n], 0, 0, 0);
        acc[m][n] = __builtin_amdgcn_mfma_f32_16x16x32_bf16(fah[m], fbl[n], acc[m][n], 0, 0, 0);
        acc[m][n] = __builtin_amdgcn_mfma_f32_16x16x32_bf16(fah[m], fbh[n], acc[m][n], 0, 0, 0);
      }
  };

  stage(0, 0);                                     // prologue
  for (int t = 0; t < 31; ++t) {
    stage((t + 1) & 1, t + 1);                     // prefetch next K-step
    __builtin_amdgcn_sched_barrier(0);
    asm volatile("s_waitcnt vmcnt(4)" ::: "memory");  // wait stage(t) only
    __builtin_amdgcn_sched_barrier(0);
    __builtin_amdgcn_s_barrier();
    compute(t & 1);
    __builtin_amdgcn_sched_barrier(0);
    __builtin_amdgcn_s_barrier();                  // protect buf before overwrite
  }
  __builtin_amdgcn_sched_barrier(0);
  asm volatile("s_waitcnt vmcnt(0)" ::: "memory");
  __builtin_amdgcn_sched_barrier(0);
  __builtin_amdgcn_s_barrier();
  compute(1);                                      // t=31

  // epilogue: store + fused per-column sum of squares
  // D row = (lane>>4)*4 + j, col = lane&15  [m89-verified layout]
  const int r0 = bm0 + wm + (kcsel << 2);
  const int c0 = bn0 + wn + rsel;
  float csq[2] = {0.f, 0.f};
#pragma unroll
  for (int m = 0; m < 2; ++m)
#pragma unroll
    for (int n = 0; n < 2; ++n)
#pragma unroll
      for (int j = 0; j < 4; ++j) {
        const float v = acc[m][n][j];
        C[(size_t)(r0 + m * 16 + j) * 1024 + c0 + n * 16] = v;
        csq[n] += v * v;
      }
  // reduce over kcsel lanes (rows within wave): lanes rsel, +16, +32, +48
#pragma unroll
  for (int n = 0; n < 2; ++n) {
    csq[n] += __shfl_xor(csq[n], 16);
    csq[n] += __shfl_xor(csq[n], 32);
  }
  if (kcsel == 0) {
#pragma unroll
    for (int n = 0; n < 2; ++n)
      atomicAdd(&var[c0 + n * 16], csq[n]);
  }
}

// ---- final: out[b,i] = (1/32) * sum_v act[i][b][v] * wout[v] ----------------
__global__ void final_kernel(const unsigned short* __restrict__ ah,
                             const unsigned short* __restrict__ al,
                             const float* __restrict__ wout, float* __restrict__ out) {
  const int b = blockIdx.x, tid = threadIdx.x;
  __shared__ float red[3][4];
  float s[3] = {0.f, 0.f, 0.f};
  for (int v = tid; v < 1024; v += 256) {
    const float w = wout[v];
    const size_t base = (size_t)b * 1024 + v;
    s[0] += (bf2f(ah[base])             + bf2f(al[base]))             * w;
    s[1] += (bf2f(ah[base + PLANE])     + bf2f(al[base + PLANE]))     * w;
    s[2] += (bf2f(ah[base + 2 * PLANE]) + bf2f(al[base + 2 * PLANE])) * w;
  }
#pragma unroll
  for (int i = 0; i < 3; ++i)
    for (int o = 32; o >= 1; o >>= 1) s[i] += __shfl_down(s[i], o);
  if ((tid & 63) == 0)
#pragma unroll
    for (int i = 0; i < 3; ++i) red[i][tid >> 6] = s[i];
  __syncthreads();
  if (tid < 3) {
    const float t = red[tid][0] + red[tid][1] + red[tid][2] + red[tid][3];
    out[b * 3 + tid] = t * 0.03125f;
  }
}

extern "C" void kernel_launch(void* const* d_in, const int* in_sizes, int n_in,
                              void* d_out, int out_size, void* d_ws, size_t ws_size,
                              hipStream_t stream) {
  const float* x    = (const float*)d_in[0];
  const float* w1   = (const float*)d_in[1];
  const float* W    = (const float*)d_in[2];
  const float* bnw  = (const float*)d_in[3];
  const float* wout = (const float*)d_in[4];
  float* out = (float*)d_out;

  char* ws = (char*)d_ws;
  float*          var = (float*)ws;                         // 6*1024 f32 (32 KB resv)
  float*          pre = (float*)(ws + 32768);               // 3072*1024 f32 (12 MB)
  unsigned short* ah  = (unsigned short*)(ws + 12615680);   // 3*1M bf16 (6 MB)
  unsigned short* al  = (unsigned short*)(ws + 18907136);   // 3*1M bf16 (6 MB)
  unsigned short* wh  = (unsigned short*)(ws + 25198592);   // 5*1M bf16 (10 MB)
  unsigned short* wl  = (unsigned short*)(ws + 35684352);   // 5*1M bf16 (10 MB)

  hipMemsetAsync(var, 0, 6 * 1024 * sizeof(float), stream);
  convert_w<<<dim3(16, 16, 5), 256, 0, stream>>>(W, wh, wl);
  layer0<<<4096, 256, 0, stream>>>(x, w1, pre);
  colsumsq<<<dim3(24, 4), 256, 0, stream>>>(pre, var);
  act_kernel<<<1024, 256, 0, stream>>>(pre, var, bnw, ah, al);
  for (int b = 0; b < 5; ++b) {
    gemm_fused<<<dim3(48, 16), 256, 0, stream>>>(
        ah, al, wh + (size_t)b * PLANE, wl + (size_t)b * PLANE,
        pre, var + (b + 1) * 1024);
    act_kernel<<<1024, 256, 0, stream>>>(pre, var + (b + 1) * 1024,
                                         bnw + (size_t)(b + 1) * 4096, ah, al);
  }
  final_kernel<<<1024, 256, 0, stream>>>(ah, al, wout, out);
}

// Round 7
// 323.395 us; speedup vs baseline: 1.0316x; 1.0316x over previous
//
#include <hip/hip_runtime.h>
#include <hip/hip_bf16.h>
#include <cstdint>
#include <cstddef>

// ---------------------------------------------------------------------------
// E3nnMLPNorm: only the l=1 (d=3) irrep path is nonzero.
// layer0(+fused colsumsq) -> [gemm(+fused colsumsq) -> bn+gate] x5 -> final
// Precision: bf16 hi+lo pairs, 3 bf16 MFMA per fragment into f32 acc.
// GEMM R7: 64x64 tile, 4 waves, 768 blocks (3/CU), *** 3-deep LDS pipeline ***
// (R4/R6 showed depth-2 exposes L3-latency every step: VALUBusy 9%,
//  step ~4000cy vs ~300cy compute. Depth-3 gives loads ~2 iterations.)
// ---------------------------------------------------------------------------

typedef short    s16x8 __attribute__((ext_vector_type(8)));
typedef float    f32x4 __attribute__((ext_vector_type(4)));

#define PLANE 1048576   // 1024*1024 elements per plane

__device__ __forceinline__ unsigned short f2bf(float f) {
  unsigned u = __builtin_bit_cast(unsigned, f);
  u += 0x7FFFu + ((u >> 16) & 1u);              // round-to-nearest-even
  return (unsigned short)(u >> 16);
}
__device__ __forceinline__ float bf2f(unsigned short h) {
  return __builtin_bit_cast(float, (unsigned)h << 16);
}

__device__ __forceinline__ void load_lds16(const void* g, void* l) {
  __builtin_amdgcn_global_load_lds(
      (const __attribute__((address_space(1))) unsigned int*)g,
      (__attribute__((address_space(3))) unsigned int*)l,
      16, 0, 0);
}

// ---- W[b,0] (f32 [u][v]) -> bf16 hi/lo [v][u] with 1/32 folded in ----------
__global__ void convert_w(const float* __restrict__ W,
                          unsigned short* __restrict__ Wh,
                          unsigned short* __restrict__ Wl) {
  __shared__ float t[64][65];
  const int u0 = blockIdx.x * 64, v0 = blockIdx.y * 64;
  const float* Wb = W + (size_t)blockIdx.z * 4194304;   // [5][4][1024][1024], irrep 0
  unsigned short* Whb = Wh + (size_t)blockIdx.z * PLANE;
  unsigned short* Wlb = Wl + (size_t)blockIdx.z * PLANE;
  const int c = threadIdx.x & 63, r4 = threadIdx.x >> 6;
#pragma unroll
  for (int i = 0; i < 16; ++i) {
    const int r = i * 4 + r4;
    t[r][c] = Wb[(size_t)(u0 + r) * 1024 + v0 + c];
  }
  __syncthreads();
#pragma unroll
  for (int i = 0; i < 16; ++i) {
    const int r = i * 4 + r4;   // local v index
    const float w = t[c][r] * 0.03125f;      // exact pow2 scale
    const unsigned short hi = f2bf(w);
    const size_t idx = (size_t)(v0 + r) * 1024 + u0 + c;
    Whb[idx] = hi;
    Wlb[idx] = f2bf(w - bf2f(hi));
  }
}

// ---- layer0 + fused colsumsq: pre[i][b][v], var[v] += sum f^2 ---------------
// grid (4 v-panels, 64 b-chunks) x 256 thr; thread owns one v, 16 b's.
__global__ void layer0_fused(const float* __restrict__ x, const float* __restrict__ w1,
                             float* __restrict__ pre, float* __restrict__ var) {
  const int v = blockIdx.x * 256 + threadIdx.x;
  const int b0 = blockIdx.y * 16;
  const float a0 = w1[v], a1 = w1[1024 + v];
  const float inv = 0.70710678118654752f;
  float ssq = 0.f;
#pragma unroll 4
  for (int bb = 0; bb < 16; ++bb) {
    const int b = b0 + bb;
    const float* xb = x + b * 6;                    // x flat [B][2][3]
#pragma unroll
    for (int i = 0; i < 3; ++i) {
      const float f = (xb[i] * a0 + xb[3 + i] * a1) * inv;
      pre[(size_t)i * PLANE + (size_t)b * 1024 + v] = f;
      ssq += f * f;
    }
  }
  atomicAdd(&var[v], ssq);
}

// ---- batchnorm scale + norm-gated sigmoid, write bf16 hi/lo (x4 vector) -----
__global__ void act_kernel(const float* __restrict__ pre, const float* __restrict__ var,
                           const float* __restrict__ bnw,
                           unsigned short* __restrict__ ah,
                           unsigned short* __restrict__ al) {
  const int idx = (blockIdx.x * 256 + threadIdx.x) * 4;   // 262144 threads x4
  const int v = idx & 1023;
  const float4 p0 = *(const float4*)&pre[idx];
  const float4 p1 = *(const float4*)&pre[idx + PLANE];
  const float4 p2 = *(const float4*)&pre[idx + 2 * PLANE];
  const float a0[4] = {p0.x, p0.y, p0.z, p0.w};
  const float a1[4] = {p1.x, p1.y, p1.z, p1.w};
  const float a2[4] = {p2.x, p2.y, p2.z, p2.w};
  unsigned short H0[4], L0[4], H1[4], L1[4], H2[4], L2[4];
#pragma unroll
  for (int j = 0; j < 4; ++j) {
    const float s = bnw[v + j] / sqrtf(var[v + j] * (1.0f / 3072.0f) + 1e-5f);
    const float f0 = a0[j] * s, f1 = a1[j] * s, f2 = a2[j] * s;
    const float n = sqrtf(f0 * f0 + f1 * f1 + f2 * f2 + 1e-8f);
    const float g = 1.0f / ((1.0f + expf(-n)) * n);   // sigmoid(n)/n
    const float o0 = f0 * g, o1 = f1 * g, o2 = f2 * g;
    H0[j] = f2bf(o0); L0[j] = f2bf(o0 - bf2f(H0[j]));
    H1[j] = f2bf(o1); L1[j] = f2bf(o1 - bf2f(H1[j]));
    H2[j] = f2bf(o2); L2[j] = f2bf(o2 - bf2f(H2[j]));
  }
  *(ushort4*)&ah[idx]             = make_ushort4(H0[0], H0[1], H0[2], H0[3]);
  *(ushort4*)&al[idx]             = make_ushort4(L0[0], L0[1], L0[2], L0[3]);
  *(ushort4*)&ah[idx + PLANE]     = make_ushort4(H1[0], H1[1], H1[2], H1[3]);
  *(ushort4*)&al[idx + PLANE]     = make_ushort4(L1[0], L1[1], L1[2], L1[3]);
  *(ushort4*)&ah[idx + 2 * PLANE] = make_ushort4(H2[0], H2[1], H2[2], H2[3]);
  *(ushort4*)&al[idx + 2 * PLANE] = make_ushort4(L2[0], L2[1], L2[2], L2[3]);
}

// ---- bf16-pair MFMA GEMM + fused column-sumsq, 64x64 tile, 3-deep pipe ------
// C[3072][1024] = (Ah+Al) * (Bh+Bl)^T ; var[col] += sum_rows C^2
__global__ __launch_bounds__(256, 3) void gemm_fused(
    const unsigned short* __restrict__ Ah, const unsigned short* __restrict__ Al,
    const unsigned short* __restrict__ Bh, const unsigned short* __restrict__ Bl,
    float* __restrict__ C, float* __restrict__ var) {
  // [buf 3][mat: aH,aL,bH,bL][rowhi 4][kc 4][rowlo 16][8 halves] = 48 KB
  __shared__ unsigned short lds[3][4][4][4][16][8];
  const int tid = threadIdx.x;
  const int bm0 = blockIdx.x * 64, bn0 = blockIdx.y * 64;
  const int lane = tid & 63, wave = tid >> 6;
  const int wm = (wave >> 1) * 32, wn = (wave & 1) * 32;
  const int rsel = lane & 15, kcsel = lane >> 4;

  f32x4 acc[2][2] = {};

  // staging: wave w covers rows [w*16, w*16+16); lane = kchunk*16 + rowlo
  const size_t stoff = ((size_t)(wave * 16 + rsel) << 11) + (kcsel << 4);
  const char* g0 = (const char*)Ah + ((size_t)bm0 << 11) + stoff;
  const char* g1 = (const char*)Al + ((size_t)bm0 << 11) + stoff;
  const char* g2 = (const char*)Bh + ((size_t)bn0 << 11) + stoff;
  const char* g3 = (const char*)Bl + ((size_t)bn0 << 11) + stoff;

  auto stage = [&](int buf, int t) {
    const int kb = t << 6;                           // byte offset along K (BK=32)
    char* base = (char*)lds + buf * 16384 + (wave << 10);  // wave-uniform
    load_lds16(g0 + kb, base);
    load_lds16(g1 + kb, base + 4096);
    load_lds16(g2 + kb, base + 8192);
    load_lds16(g3 + kb, base + 12288);
  };

  // fragment offsets: mat*4096 + rowhi*1024 + kcsel*256 + rsel*16 (bytes)
  const int fo = kcsel * 256 + rsel * 16;
  auto compute = [&](int buf) {
    const char* p = (const char*)lds + buf * 16384;
    s16x8 fah[2], fal[2], fbh[2], fbl[2];
#pragma unroll
    for (int m = 0; m < 2; ++m) {
      fah[m] = *(const s16x8*)(p         + ((wm >> 4) + m) * 1024 + fo);
      fal[m] = *(const s16x8*)(p + 4096  + ((wm >> 4) + m) * 1024 + fo);
    }
#pragma unroll
    for (int n = 0; n < 2; ++n) {
      fbh[n] = *(const s16x8*)(p + 8192  + ((wn >> 4) + n) * 1024 + fo);
      fbl[n] = *(const s16x8*)(p + 12288 + ((wn >> 4) + n) * 1024 + fo);
    }
#pragma unroll
    for (int m = 0; m < 2; ++m)
#pragma unroll
      for (int n = 0; n < 2; ++n) {
        acc[m][n] = __builtin_amdgcn_mfma_f32_16x16x32_bf16(fal[m], fbh[n], acc[m][n], 0, 0, 0);
        acc[m][n] = __builtin_amdgcn_mfma_f32_16x16x32_bf16(fah[m], fbl[n], acc[m][n], 0, 0, 0);
        acc[m][n] = __builtin_amdgcn_mfma_f32_16x16x32_bf16(fah[m], fbh[n], acc[m][n], 0, 0, 0);
      }
  };

  // prologue: fill 2 buffers ahead
  stage(0, 0);
  stage(1, 1);
  int cb = 0, sb = 2;                              // compute buf, stage buf
  for (int t = 0; t < 30; ++t) {
    stage(sb, t + 2);                              // issue 2 steps ahead
    __builtin_amdgcn_sched_barrier(0);
    asm volatile("s_waitcnt vmcnt(8)" ::: "memory");  // wait stage(t) only
    __builtin_amdgcn_sched_barrier(0);
    __builtin_amdgcn_s_barrier();
    compute(cb);
    __builtin_amdgcn_sched_barrier(0);
    __builtin_amdgcn_s_barrier();                  // protect buf before overwrite
    sb = cb;
    cb = (cb == 2) ? 0 : cb + 1;
  }
  // t=30: outstanding = stage(31)'s 4 loads
  asm volatile("s_waitcnt vmcnt(4)" ::: "memory");
  __builtin_amdgcn_sched_barrier(0);
  __builtin_amdgcn_s_barrier();
  compute(0);                                      // kt=30 lives in buf 0
  // t=31:
  asm volatile("s_waitcnt vmcnt(0)" ::: "memory");
  __builtin_amdgcn_sched_barrier(0);
  __builtin_amdgcn_s_barrier();
  compute(1);                                      // kt=31 lives in buf 1

  // epilogue: store + fused per-column sum of squares
  // D row = (lane>>4)*4 + j, col = lane&15  [m89-verified layout]
  const int r0 = bm0 + wm + (kcsel << 2);
  const int c0 = bn0 + wn + rsel;
  float csq[2] = {0.f, 0.f};
#pragma unroll
  for (int m = 0; m < 2; ++m)
#pragma unroll
    for (int n = 0; n < 2; ++n)
#pragma unroll
      for (int j = 0; j < 4; ++j) {
        const float v = acc[m][n][j];
        C[(size_t)(r0 + m * 16 + j) * 1024 + c0 + n * 16] = v;
        csq[n] += v * v;
      }
#pragma unroll
  for (int n = 0; n < 2; ++n) {
    csq[n] += __shfl_xor(csq[n], 16);
    csq[n] += __shfl_xor(csq[n], 32);
  }
  if (kcsel == 0) {
#pragma unroll
    for (int n = 0; n < 2; ++n)
      atomicAdd(&var[c0 + n * 16], csq[n]);
  }
}

// ---- final: out[b,i] = (1/32) * sum_v act[i][b][v] * wout[v] ----------------
__global__ void final_kernel(const unsigned short* __restrict__ ah,
                             const unsigned short* __restrict__ al,
                             const float* __restrict__ wout, float* __restrict__ out) {
  const int b = blockIdx.x, tid = threadIdx.x;
  __shared__ float red[3][4];
  float s[3] = {0.f, 0.f, 0.f};
  for (int v = tid; v < 1024; v += 256) {
    const float w = wout[v];
    const size_t base = (size_t)b * 1024 + v;
    s[0] += (bf2f(ah[base])             + bf2f(al[base]))             * w;
    s[1] += (bf2f(ah[base + PLANE])     + bf2f(al[base + PLANE]))     * w;
    s[2] += (bf2f(ah[base + 2 * PLANE]) + bf2f(al[base + 2 * PLANE])) * w;
  }
#pragma unroll
  for (int i = 0; i < 3; ++i)
    for (int o = 32; o >= 1; o >>= 1) s[i] += __shfl_down(s[i], o);
  if ((tid & 63) == 0)
#pragma unroll
    for (int i = 0; i < 3; ++i) red[i][tid >> 6] = s[i];
  __syncthreads();
  if (tid < 3) {
    const float t = red[tid][0] + red[tid][1] + red[tid][2] + red[tid][3];
    out[b * 3 + tid] = t * 0.03125f;
  }
}

extern "C" void kernel_launch(void* const* d_in, const int* in_sizes, int n_in,
                              void* d_out, int out_size, void* d_ws, size_t ws_size,
                              hipStream_t stream) {
  const float* x    = (const float*)d_in[0];
  const float* w1   = (const float*)d_in[1];
  const float* W    = (const float*)d_in[2];
  const float* bnw  = (const float*)d_in[3];
  const float* wout = (const float*)d_in[4];
  float* out = (float*)d_out;

  char* ws = (char*)d_ws;
  float*          var = (float*)ws;                         // 6*1024 f32 (32 KB resv)
  float*          pre = (float*)(ws + 32768);               // 3072*1024 f32 (12 MB)
  unsigned short* ah  = (unsigned short*)(ws + 12615680);   // 3*1M bf16 (6 MB)
  unsigned short* al  = (unsigned short*)(ws + 18907136);   // 3*1M bf16 (6 MB)
  unsigned short* wh  = (unsigned short*)(ws + 25198592);   // 5*1M bf16 (10 MB)
  unsigned short* wl  = (unsigned short*)(ws + 35684352);   // 5*1M bf16 (10 MB)

  hipMemsetAsync(var, 0, 6 * 1024 * sizeof(float), stream);
  convert_w<<<dim3(16, 16, 5), 256, 0, stream>>>(W, wh, wl);
  layer0_fused<<<dim3(4, 64), 256, 0, stream>>>(x, w1, pre, var);
  act_kernel<<<1024, 256, 0, stream>>>(pre, var, bnw, ah, al);
  for (int b = 0; b < 5; ++b) {
    gemm_fused<<<dim3(48, 16), 256, 0, stream>>>(
        ah, al, wh + (size_t)b * PLANE, wl + (size_t)b * PLANE,
        pre, var + (b + 1) * 1024);
    act_kernel<<<1024, 256, 0, stream>>>(pre, var + (b + 1) * 1024,
                                         bnw + (size_t)(b + 1) * 4096, ah, al);
  }
  final_kernel<<<1024, 256, 0, stream>>>(ah, al, wout, out);
}

// Round 8
// 314.377 us; speedup vs baseline: 1.0612x; 1.0287x over previous
//
#include <hip/hip_runtime.h>
#include <hip/hip_bf16.h>
#include <cstdint>
#include <cstddef>

// ---------------------------------------------------------------------------
// E3nnMLPNorm: only the l=1 (d=3) irrep path is nonzero.
// layer0(+fused colsumsq) -> [gemm(+fused colsumsq) -> bn+gate] x5 -> final
// Precision: bf16 hi+lo pairs, 3 bf16 MFMA per fragment into f32 acc.
// GEMM R8: R7 structure (64x64 tile, 4 waves, 768 blocks, 3-deep pipeline)
// + XCD-STRIPED block mapping: xcd x (= bid%8 round-robin) owns m-tiles
// [6x, 6x+6) — its 96 co-resident blocks share a 1.5 MB A-stripe + 4 MB B
// ~= L2 capacity, converting L3/HBM staging traffic (393 MB @ 7.4 TB/s,
// the R4-R7 invariant bottleneck) into L2 hits.
// ---------------------------------------------------------------------------

typedef short    s16x8 __attribute__((ext_vector_type(8)));
typedef float    f32x4 __attribute__((ext_vector_type(4)));

#define PLANE 1048576   // 1024*1024 elements per plane

__device__ __forceinline__ unsigned short f2bf(float f) {
  unsigned u = __builtin_bit_cast(unsigned, f);
  u += 0x7FFFu + ((u >> 16) & 1u);              // round-to-nearest-even
  return (unsigned short)(u >> 16);
}
__device__ __forceinline__ float bf2f(unsigned short h) {
  return __builtin_bit_cast(float, (unsigned)h << 16);
}

__device__ __forceinline__ void load_lds16(const void* g, void* l) {
  __builtin_amdgcn_global_load_lds(
      (const __attribute__((address_space(1))) unsigned int*)g,
      (__attribute__((address_space(3))) unsigned int*)l,
      16, 0, 0);
}

// ---- W[b,0] (f32 [u][v]) -> bf16 hi/lo [v][u] with 1/32 folded in ----------
__global__ void convert_w(const float* __restrict__ W,
                          unsigned short* __restrict__ Wh,
                          unsigned short* __restrict__ Wl) {
  __shared__ float t[64][65];
  const int u0 = blockIdx.x * 64, v0 = blockIdx.y * 64;
  const float* Wb = W + (size_t)blockIdx.z * 4194304;   // [5][4][1024][1024], irrep 0
  unsigned short* Whb = Wh + (size_t)blockIdx.z * PLANE;
  unsigned short* Wlb = Wl + (size_t)blockIdx.z * PLANE;
  const int c = threadIdx.x & 63, r4 = threadIdx.x >> 6;
#pragma unroll
  for (int i = 0; i < 16; ++i) {
    const int r = i * 4 + r4;
    t[r][c] = Wb[(size_t)(u0 + r) * 1024 + v0 + c];
  }
  __syncthreads();
#pragma unroll
  for (int i = 0; i < 16; ++i) {
    const int r = i * 4 + r4;   // local v index
    const float w = t[c][r] * 0.03125f;      // exact pow2 scale
    const unsigned short hi = f2bf(w);
    const size_t idx = (size_t)(v0 + r) * 1024 + u0 + c;
    Whb[idx] = hi;
    Wlb[idx] = f2bf(w - bf2f(hi));
  }
}

// ---- layer0 + fused colsumsq: pre[i][b][v], var[v] += sum f^2 ---------------
__global__ void layer0_fused(const float* __restrict__ x, const float* __restrict__ w1,
                             float* __restrict__ pre, float* __restrict__ var) {
  const int v = blockIdx.x * 256 + threadIdx.x;
  const int b0 = blockIdx.y * 16;
  const float a0 = w1[v], a1 = w1[1024 + v];
  const float inv = 0.70710678118654752f;
  float ssq = 0.f;
#pragma unroll 4
  for (int bb = 0; bb < 16; ++bb) {
    const int b = b0 + bb;
    const float* xb = x + b * 6;                    // x flat [B][2][3]
#pragma unroll
    for (int i = 0; i < 3; ++i) {
      const float f = (xb[i] * a0 + xb[3 + i] * a1) * inv;
      pre[(size_t)i * PLANE + (size_t)b * 1024 + v] = f;
      ssq += f * f;
    }
  }
  atomicAdd(&var[v], ssq);
}

// ---- batchnorm scale + norm-gated sigmoid, write bf16 hi/lo (x4 vector) -----
__global__ void act_kernel(const float* __restrict__ pre, const float* __restrict__ var,
                           const float* __restrict__ bnw,
                           unsigned short* __restrict__ ah,
                           unsigned short* __restrict__ al) {
  const int idx = (blockIdx.x * 256 + threadIdx.x) * 4;   // 262144 threads x4
  const int v = idx & 1023;
  const float4 p0 = *(const float4*)&pre[idx];
  const float4 p1 = *(const float4*)&pre[idx + PLANE];
  const float4 p2 = *(const float4*)&pre[idx + 2 * PLANE];
  const float a0[4] = {p0.x, p0.y, p0.z, p0.w};
  const float a1[4] = {p1.x, p1.y, p1.z, p1.w};
  const float a2[4] = {p2.x, p2.y, p2.z, p2.w};
  unsigned short H0[4], L0[4], H1[4], L1[4], H2[4], L2[4];
#pragma unroll
  for (int j = 0; j < 4; ++j) {
    const float s = bnw[v + j] / sqrtf(var[v + j] * (1.0f / 3072.0f) + 1e-5f);
    const float f0 = a0[j] * s, f1 = a1[j] * s, f2 = a2[j] * s;
    const float n = sqrtf(f0 * f0 + f1 * f1 + f2 * f2 + 1e-8f);
    const float g = 1.0f / ((1.0f + expf(-n)) * n);   // sigmoid(n)/n
    const float o0 = f0 * g, o1 = f1 * g, o2 = f2 * g;
    H0[j] = f2bf(o0); L0[j] = f2bf(o0 - bf2f(H0[j]));
    H1[j] = f2bf(o1); L1[j] = f2bf(o1 - bf2f(H1[j]));
    H2[j] = f2bf(o2); L2[j] = f2bf(o2 - bf2f(H2[j]));
  }
  *(ushort4*)&ah[idx]             = make_ushort4(H0[0], H0[1], H0[2], H0[3]);
  *(ushort4*)&al[idx]             = make_ushort4(L0[0], L0[1], L0[2], L0[3]);
  *(ushort4*)&ah[idx + PLANE]     = make_ushort4(H1[0], H1[1], H1[2], H1[3]);
  *(ushort4*)&al[idx + PLANE]     = make_ushort4(L1[0], L1[1], L1[2], L1[3]);
  *(ushort4*)&ah[idx + 2 * PLANE] = make_ushort4(H2[0], H2[1], H2[2], H2[3]);
  *(ushort4*)&al[idx + 2 * PLANE] = make_ushort4(L2[0], L2[1], L2[2], L2[3]);
}

// ---- bf16-pair MFMA GEMM + fused column-sumsq, 64x64, 3-deep, XCD-striped ---
// C[3072][1024] = (Ah+Al) * (Bh+Bl)^T ; var[col] += sum_rows C^2
__global__ __launch_bounds__(256, 3) void gemm_fused(
    const unsigned short* __restrict__ Ah, const unsigned short* __restrict__ Al,
    const unsigned short* __restrict__ Bh, const unsigned short* __restrict__ Bl,
    float* __restrict__ C, float* __restrict__ var) {
  // [buf 3][mat: aH,aL,bH,bL][rowhi 4][kc 4][rowlo 16][8 halves] = 48 KB
  __shared__ unsigned short lds[3][4][4][4][16][8];
  const int tid = threadIdx.x;
  // XCD-stripe swizzle: hw round-robin assigns bid%8 -> XCD. XCD x owns
  // m-tiles [6x, 6x+6) x all 16 n-tiles: per-XCD set = 1.5 MB A + 4 MB B.
  const int bid = blockIdx.x;
  const int xcd = bid & 7, q = bid >> 3;          // q in 0..95
  const int bm0 = (xcd * 6 + (q % 6)) * 64;
  const int bn0 = (q / 6) * 64;
  const int lane = tid & 63, wave = tid >> 6;
  const int wm = (wave >> 1) * 32, wn = (wave & 1) * 32;
  const int rsel = lane & 15, kcsel = lane >> 4;

  f32x4 acc[2][2] = {};

  // staging: wave w covers rows [w*16, w*16+16); lane = kchunk*16 + rowlo
  const size_t stoff = ((size_t)(wave * 16 + rsel) << 11) + (kcsel << 4);
  const char* g0 = (const char*)Ah + ((size_t)bm0 << 11) + stoff;
  const char* g1 = (const char*)Al + ((size_t)bm0 << 11) + stoff;
  const char* g2 = (const char*)Bh + ((size_t)bn0 << 11) + stoff;
  const char* g3 = (const char*)Bl + ((size_t)bn0 << 11) + stoff;

  auto stage = [&](int buf, int t) {
    const int kb = t << 6;                           // byte offset along K (BK=32)
    char* base = (char*)lds + buf * 16384 + (wave << 10);  // wave-uniform
    load_lds16(g0 + kb, base);
    load_lds16(g1 + kb, base + 4096);
    load_lds16(g2 + kb, base + 8192);
    load_lds16(g3 + kb, base + 12288);
  };

  // fragment offsets: mat*4096 + rowhi*1024 + kcsel*256 + rsel*16 (bytes)
  const int fo = kcsel * 256 + rsel * 16;
  auto compute = [&](int buf) {
    const char* p = (const char*)lds + buf * 16384;
    s16x8 fah[2], fal[2], fbh[2], fbl[2];
#pragma unroll
    for (int m = 0; m < 2; ++m) {
      fah[m] = *(const s16x8*)(p         + ((wm >> 4) + m) * 1024 + fo);
      fal[m] = *(const s16x8*)(p + 4096  + ((wm >> 4) + m) * 1024 + fo);
    }
#pragma unroll
    for (int n = 0; n < 2; ++n) {
      fbh[n] = *(const s16x8*)(p + 8192  + ((wn >> 4) + n) * 1024 + fo);
      fbl[n] = *(const s16x8*)(p + 12288 + ((wn >> 4) + n) * 1024 + fo);
    }
#pragma unroll
    for (int m = 0; m < 2; ++m)
#pragma unroll
      for (int n = 0; n < 2; ++n) {
        acc[m][n] = __builtin_amdgcn_mfma_f32_16x16x32_bf16(fal[m], fbh[n], acc[m][n], 0, 0, 0);
        acc[m][n] = __builtin_amdgcn_mfma_f32_16x16x32_bf16(fah[m], fbl[n], acc[m][n], 0, 0, 0);
        acc[m][n] = __builtin_amdgcn_mfma_f32_16x16x32_bf16(fah[m], fbh[n], acc[m][n], 0, 0, 0);
      }
  };

  // prologue: fill 2 buffers ahead
  stage(0, 0);
  stage(1, 1);
  int cb = 0, sb = 2;                              // compute buf, stage buf
  for (int t = 0; t < 30; ++t) {
    stage(sb, t + 2);                              // issue 2 steps ahead
    __builtin_amdgcn_sched_barrier(0);
    asm volatile("s_waitcnt vmcnt(8)" ::: "memory");  // wait stage(t) only
    __builtin_amdgcn_sched_barrier(0);
    __builtin_amdgcn_s_barrier();
    compute(cb);
    __builtin_amdgcn_sched_barrier(0);
    __builtin_amdgcn_s_barrier();                  // protect buf before overwrite
    sb = cb;
    cb = (cb == 2) ? 0 : cb + 1;
  }
  // t=30: outstanding = stage(31)'s 4 loads
  asm volatile("s_waitcnt vmcnt(4)" ::: "memory");
  __builtin_amdgcn_sched_barrier(0);
  __builtin_amdgcn_s_barrier();
  compute(0);                                      // kt=30 lives in buf 0
  // t=31:
  asm volatile("s_waitcnt vmcnt(0)" ::: "memory");
  __builtin_amdgcn_sched_barrier(0);
  __builtin_amdgcn_s_barrier();
  compute(1);                                      // kt=31 lives in buf 1

  // epilogue: store + fused per-column sum of squares
  // D row = (lane>>4)*4 + j, col = lane&15  [m89-verified layout]
  const int r0 = bm0 + wm + (kcsel << 2);
  const int c0 = bn0 + wn + rsel;
  float csq[2] = {0.f, 0.f};
#pragma unroll
  for (int m = 0; m < 2; ++m)
#pragma unroll
    for (int n = 0; n < 2; ++n)
#pragma unroll
      for (int j = 0; j < 4; ++j) {
        const float v = acc[m][n][j];
        C[(size_t)(r0 + m * 16 + j) * 1024 + c0 + n * 16] = v;
        csq[n] += v * v;
      }
#pragma unroll
  for (int n = 0; n < 2; ++n) {
    csq[n] += __shfl_xor(csq[n], 16);
    csq[n] += __shfl_xor(csq[n], 32);
  }
  if (kcsel == 0) {
#pragma unroll
    for (int n = 0; n < 2; ++n)
      atomicAdd(&var[c0 + n * 16], csq[n]);
  }
}

// ---- final: out[b,i] = (1/32) * sum_v act[i][b][v] * wout[v] ----------------
__global__ void final_kernel(const unsigned short* __restrict__ ah,
                             const unsigned short* __restrict__ al,
                             const float* __restrict__ wout, float* __restrict__ out) {
  const int b = blockIdx.x, tid = threadIdx.x;
  __shared__ float red[3][4];
  float s[3] = {0.f, 0.f, 0.f};
  for (int v = tid; v < 1024; v += 256) {
    const float w = wout[v];
    const size_t base = (size_t)b * 1024 + v;
    s[0] += (bf2f(ah[base])             + bf2f(al[base]))             * w;
    s[1] += (bf2f(ah[base + PLANE])     + bf2f(al[base + PLANE]))     * w;
    s[2] += (bf2f(ah[base + 2 * PLANE]) + bf2f(al[base + 2 * PLANE])) * w;
  }
#pragma unroll
  for (int i = 0; i < 3; ++i)
    for (int o = 32; o >= 1; o >>= 1) s[i] += __shfl_down(s[i], o);
  if ((tid & 63) == 0)
#pragma unroll
    for (int i = 0; i < 3; ++i) red[i][tid >> 6] = s[i];
  __syncthreads();
  if (tid < 3) {
    const float t = red[tid][0] + red[tid][1] + red[tid][2] + red[tid][3];
    out[b * 3 + tid] = t * 0.03125f;
  }
}

extern "C" void kernel_launch(void* const* d_in, const int* in_sizes, int n_in,
                              void* d_out, int out_size, void* d_ws, size_t ws_size,
                              hipStream_t stream) {
  const float* x    = (const float*)d_in[0];
  const float* w1   = (const float*)d_in[1];
  const float* W    = (const float*)d_in[2];
  const float* bnw  = (const float*)d_in[3];
  const float* wout = (const float*)d_in[4];
  float* out = (float*)d_out;

  char* ws = (char*)d_ws;
  float*          var = (float*)ws;                         // 6*1024 f32 (32 KB resv)
  float*          pre = (float*)(ws + 32768);               // 3072*1024 f32 (12 MB)
  unsigned short* ah  = (unsigned short*)(ws + 12615680);   // 3*1M bf16 (6 MB)
  unsigned short* al  = (unsigned short*)(ws + 18907136);   // 3*1M bf16 (6 MB)
  unsigned short* wh  = (unsigned short*)(ws + 25198592);   // 5*1M bf16 (10 MB)
  unsigned short* wl  = (unsigned short*)(ws + 35684352);   // 5*1M bf16 (10 MB)

  hipMemsetAsync(var, 0, 6 * 1024 * sizeof(float), stream);
  convert_w<<<dim3(16, 16, 5), 256, 0, stream>>>(W, wh, wl);
  layer0_fused<<<dim3(4, 64), 256, 0, stream>>>(x, w1, pre, var);
  act_kernel<<<1024, 256, 0, stream>>>(pre, var, bnw, ah, al);
  for (int b = 0; b < 5; ++b) {
    gemm_fused<<<768, 256, 0, stream>>>(
        ah, al, wh + (size_t)b * PLANE, wl + (size_t)b * PLANE,
        pre, var + (b + 1) * 1024);
    act_kernel<<<1024, 256, 0, stream>>>(pre, var + (b + 1) * 1024,
                                         bnw + (size_t)(b + 1) * 4096, ah, al);
  }
  final_kernel<<<1024, 256, 0, stream>>>(ah, al, wout, out);
}

// Round 9
// 207.625 us; speedup vs baseline: 1.6068x; 1.5142x over previous
//
#include <hip/hip_runtime.h>
#include <hip/hip_bf16.h>
#include <cstdint>
#include <cstddef>

// ---------------------------------------------------------------------------
// E3nnMLPNorm: only the l=1 (d=3) irrep path is nonzero.
// layer0(+fused colsumsq) -> [gemm(+fused colsumsq) -> bn+gate] x5 -> final
// Precision: bf16 hi+lo pairs, 3 bf16 MFMA per fragment into f32 acc.
// R9: K-BLOCKED operand layout. R3-R8 all staged with 2KB-strided 16-64B
// chunks -> channel-conflict queuing (~700 GB/s effective, every pipe <15%).
// A and B are repacked into [mt][kt][w][kc][rl] 4KB blocks so every
// global_load_lds reads 1KB contiguous per wave. LDS image & compute()
// identical to R7 (bank-conflict-free, verified 0 in counters).
// ---------------------------------------------------------------------------

typedef short    s16x8 __attribute__((ext_vector_type(8)));
typedef float    f32x4 __attribute__((ext_vector_type(4)));

#define PLANE 1048576   // 1024*1024 elements per plane

__device__ __forceinline__ unsigned short f2bf(float f) {
  unsigned u = __builtin_bit_cast(unsigned, f);
  u += 0x7FFFu + ((u >> 16) & 1u);              // round-to-nearest-even
  return (unsigned short)(u >> 16);
}
__device__ __forceinline__ float bf2f(unsigned short h) {
  return __builtin_bit_cast(float, (unsigned)h << 16);
}

// byte offset of element (row, k) in the K-blocked bf16 layout:
// [row>>6][k>>5][(row>>4)&3][(k>>3)&3][row&15][k&7]
__device__ __forceinline__ size_t ablk(int row, int k) {
  return ((size_t)(row >> 6) << 17) + ((size_t)(k >> 5) << 12)
       + ((size_t)((row >> 4) & 3) << 10) + ((size_t)((k >> 3) & 3) << 8)
       + ((size_t)(row & 15) << 4) + ((size_t)(k & 7) << 1);
}

__device__ __forceinline__ void load_lds16(const void* g, void* l) {
  __builtin_amdgcn_global_load_lds(
      (const __attribute__((address_space(1))) unsigned int*)g,
      (__attribute__((address_space(3))) unsigned int*)l,
      16, 0, 0);
}

// ---- W[b,0] (f32 [u][v]) -> blocked bf16 hi/lo (row=v, k=u), 1/32 folded ----
__global__ void convert_w(const float* __restrict__ W,
                          unsigned short* __restrict__ Wh,
                          unsigned short* __restrict__ Wl) {
  __shared__ float t[64][65];
  const int u0 = blockIdx.x * 64, v0 = blockIdx.y * 64;
  const float* Wb = W + (size_t)blockIdx.z * 4194304;   // [5][4][1024][1024], irrep 0
  char* Whb = (char*)(Wh + (size_t)blockIdx.z * PLANE);
  char* Wlb = (char*)(Wl + (size_t)blockIdx.z * PLANE);
  const int c = threadIdx.x & 63, r4 = threadIdx.x >> 6;
#pragma unroll
  for (int i = 0; i < 16; ++i) {
    const int r = i * 4 + r4;
    t[r][c] = Wb[(size_t)(u0 + r) * 1024 + v0 + c];
  }
  __syncthreads();
#pragma unroll
  for (int i = 0; i < 16; ++i) {
    const int r = i * 4 + r4;   // local v index
    const float w = t[c][r] * 0.03125f;      // exact pow2 scale
    const unsigned short hi = f2bf(w);
    const size_t off = ablk(v0 + r, u0 + c);
    *(unsigned short*)(Whb + off) = hi;
    *(unsigned short*)(Wlb + off) = f2bf(w - bf2f(hi));
  }
}

// ---- layer0 + fused colsumsq: pre[i][b][v] (linear f32), var[v] += sum f^2 --
__global__ void layer0_fused(const float* __restrict__ x, const float* __restrict__ w1,
                             float* __restrict__ pre, float* __restrict__ var) {
  const int v = blockIdx.x * 256 + threadIdx.x;
  const int b0 = blockIdx.y * 16;
  const float a0 = w1[v], a1 = w1[1024 + v];
  const float inv = 0.70710678118654752f;
  float ssq = 0.f;
#pragma unroll 4
  for (int bb = 0; bb < 16; ++bb) {
    const int b = b0 + bb;
    const float* xb = x + b * 6;                    // x flat [B][2][3]
#pragma unroll
    for (int i = 0; i < 3; ++i) {
      const float f = (xb[i] * a0 + xb[3 + i] * a1) * inv;
      pre[(size_t)i * PLANE + (size_t)b * 1024 + v] = f;
      ssq += f * f;
    }
  }
  atomicAdd(&var[v], ssq);
}

// ---- batchnorm + norm-gated sigmoid: pre (linear) -> blocked bf16 hi/lo -----
// block: 16 b x 128 v; thread: b = 16bx + (tid&15), v0 = 128by + (tid>>4)*8.
__global__ void act_kernel(const float* __restrict__ pre, const float* __restrict__ var,
                           const float* __restrict__ bnw,
                           char* __restrict__ ah, char* __restrict__ al) {
  const int tid = threadIdx.x;
  const int b  = blockIdx.x * 16 + (tid & 15);
  const int v0 = blockIdx.y * 128 + (tid >> 4) * 8;
  float s[8];
#pragma unroll
  for (int j = 0; j < 8; ++j)
    s[j] = bnw[v0 + j] / sqrtf(var[v0 + j] * (1.0f / 3072.0f) + 1e-5f);
  float f[3][8];
#pragma unroll
  for (int i = 0; i < 3; ++i) {
    const float4 p0 = *(const float4*)&pre[(size_t)i * PLANE + (size_t)b * 1024 + v0];
    const float4 p1 = *(const float4*)&pre[(size_t)i * PLANE + (size_t)b * 1024 + v0 + 4];
    f[i][0] = p0.x * s[0]; f[i][1] = p0.y * s[1]; f[i][2] = p0.z * s[2]; f[i][3] = p0.w * s[3];
    f[i][4] = p1.x * s[4]; f[i][5] = p1.y * s[5]; f[i][6] = p1.z * s[6]; f[i][7] = p1.w * s[7];
  }
#pragma unroll
  for (int j = 0; j < 8; ++j) {
    const float n = sqrtf(f[0][j] * f[0][j] + f[1][j] * f[1][j] + f[2][j] * f[2][j] + 1e-8f);
    const float g = 1.0f / ((1.0f + expf(-n)) * n);   // sigmoid(n)/n
    f[0][j] *= g; f[1][j] *= g; f[2][j] *= g;
  }
#pragma unroll
  for (int i = 0; i < 3; ++i) {
    s16x8 hi, lo;
#pragma unroll
    for (int j = 0; j < 8; ++j) {
      const unsigned short h = f2bf(f[i][j]);
      hi[j] = (short)h;
      lo[j] = (short)f2bf(f[i][j] - bf2f(h));
    }
    const size_t off = ablk(i * 1024 + b, v0);
    *(s16x8*)(ah + off) = hi;
    *(s16x8*)(al + off) = lo;
  }
}

// ---- bf16-pair MFMA GEMM + fused column-sumsq, blocked operands -------------
// C[3072][1024] = (Ah+Al) * (Bh+Bl)^T ; var[col] += sum_rows C^2
__global__ __launch_bounds__(256, 3) void gemm_fused(
    const char* __restrict__ Ah, const char* __restrict__ Al,
    const char* __restrict__ Bh, const char* __restrict__ Bl,
    float* __restrict__ C, float* __restrict__ var) {
  // [buf 3][mat: aH,aL,bH,bL][w 4][kc 4][rl 16][8 halves] = 48 KB
  __shared__ unsigned short lds[3][4][4][4][16][8];
  const int tid = threadIdx.x;
  const int bid = blockIdx.x;
  const int xcd = bid & 7, q = bid >> 3;          // q in 0..95
  const int bm0 = (xcd * 6 + (q % 6)) * 64;
  const int bn0 = (q / 6) * 64;
  const int lane = tid & 63, wave = tid >> 6;
  const int wm = (wave >> 1) * 32, wn = (wave & 1) * 32;
  const int rsel = lane & 15, kcsel = lane >> 4;

  f32x4 acc[2][2] = {};

  // blocked staging bases: tile row-block (<<17) + wave (<<10) + lane (<<4);
  // each stage load reads 1KB CONTIGUOUS per wave.
  const size_t abase = ((size_t)(bm0 >> 6) << 17) + (wave << 10) + (lane << 4);
  const size_t bbase = ((size_t)(bn0 >> 6) << 17) + (wave << 10) + (lane << 4);
  const char* g0 = Ah + abase;
  const char* g1 = Al + abase;
  const char* g2 = Bh + bbase;
  const char* g3 = Bl + bbase;

  auto stage = [&](int buf, int t) {
    const size_t kb = (size_t)t << 12;               // 4KB per K-step block
    char* base = (char*)lds + buf * 16384 + (wave << 10);  // wave-uniform
    load_lds16(g0 + kb, base);
    load_lds16(g1 + kb, base + 4096);
    load_lds16(g2 + kb, base + 8192);
    load_lds16(g3 + kb, base + 12288);
  };

  // fragment offsets: mat*4096 + rowgrp*1024 + kcsel*256 + rsel*16 (bytes)
  const int fo = kcsel * 256 + rsel * 16;
  auto compute = [&](int buf) {
    const char* p = (const char*)lds + buf * 16384;
    s16x8 fah[2], fal[2], fbh[2], fbl[2];
#pragma unroll
    for (int m = 0; m < 2; ++m) {
      fah[m] = *(const s16x8*)(p         + ((wm >> 4) + m) * 1024 + fo);
      fal[m] = *(const s16x8*)(p + 4096  + ((wm >> 4) + m) * 1024 + fo);
    }
#pragma unroll
    for (int n = 0; n < 2; ++n) {
      fbh[n] = *(const s16x8*)(p + 8192  + ((wn >> 4) + n) * 1024 + fo);
      fbl[n] = *(const s16x8*)(p + 12288 + ((wn >> 4) + n) * 1024 + fo);
    }
#pragma unroll
    for (int m = 0; m < 2; ++m)
#pragma unroll
      for (int n = 0; n < 2; ++n) {
        acc[m][n] = __builtin_amdgcn_mfma_f32_16x16x32_bf16(fal[m], fbh[n], acc[m][n], 0, 0, 0);
        acc[m][n] = __builtin_amdgcn_mfma_f32_16x16x32_bf16(fah[m], fbl[n], acc[m][n], 0, 0, 0);
        acc[m][n] = __builtin_amdgcn_mfma_f32_16x16x32_bf16(fah[m], fbh[n], acc[m][n], 0, 0, 0);
      }
  };

  // prologue: fill 2 buffers ahead
  stage(0, 0);
  stage(1, 1);
  int cb = 0, sb = 2;                              // compute buf, stage buf
  for (int t = 0; t < 30; ++t) {
    stage(sb, t + 2);                              // issue 2 steps ahead
    __builtin_amdgcn_sched_barrier(0);
    asm volatile("s_waitcnt vmcnt(8)" ::: "memory");  // wait stage(t) only
    __builtin_amdgcn_sched_barrier(0);
    __builtin_amdgcn_s_barrier();
    compute(cb);
    __builtin_amdgcn_sched_barrier(0);
    __builtin_amdgcn_s_barrier();                  // protect buf before overwrite
    sb = cb;
    cb = (cb == 2) ? 0 : cb + 1;
  }
  // t=30: outstanding = stage(31)'s 4 loads
  asm volatile("s_waitcnt vmcnt(4)" ::: "memory");
  __builtin_amdgcn_sched_barrier(0);
  __builtin_amdgcn_s_barrier();
  compute(0);                                      // kt=30 lives in buf 0
  // t=31:
  asm volatile("s_waitcnt vmcnt(0)" ::: "memory");
  __builtin_amdgcn_sched_barrier(0);
  __builtin_amdgcn_s_barrier();
  compute(1);                                      // kt=31 lives in buf 1

  // epilogue: store + fused per-column sum of squares
  // D row = (lane>>4)*4 + j, col = lane&15  [m89-verified layout]
  const int r0 = bm0 + wm + (kcsel << 2);
  const int c0 = bn0 + wn + rsel;
  float csq[2] = {0.f, 0.f};
#pragma unroll
  for (int m = 0; m < 2; ++m)
#pragma unroll
    for (int n = 0; n < 2; ++n)
#pragma unroll
      for (int j = 0; j < 4; ++j) {
        const float v = acc[m][n][j];
        C[(size_t)(r0 + m * 16 + j) * 1024 + c0 + n * 16] = v;
        csq[n] += v * v;
      }
#pragma unroll
  for (int n = 0; n < 2; ++n) {
    csq[n] += __shfl_xor(csq[n], 16);
    csq[n] += __shfl_xor(csq[n], 32);
  }
  if (kcsel == 0) {
#pragma unroll
    for (int n = 0; n < 2; ++n)
      atomicAdd(&var[c0 + n * 16], csq[n]);
  }
}

// ---- final: out[b,i] = (1/32) * sum_v act[i][b][v] * wout[v] ----------------
__global__ void final_kernel(const char* __restrict__ ah, const char* __restrict__ al,
                             const float* __restrict__ wout, float* __restrict__ out) {
  const int b = blockIdx.x, tid = threadIdx.x;
  __shared__ float red[3][4];
  float s[3] = {0.f, 0.f, 0.f};
  if (tid < 128) {
    const int v0 = tid * 8;
#pragma unroll
    for (int i = 0; i < 3; ++i) {
      const size_t off = ablk(i * 1024 + b, v0);
      const s16x8 hi = *(const s16x8*)(ah + off);
      const s16x8 lo = *(const s16x8*)(al + off);
#pragma unroll
      for (int j = 0; j < 8; ++j)
        s[i] += (bf2f((unsigned short)hi[j]) + bf2f((unsigned short)lo[j])) * wout[v0 + j];
    }
  }
#pragma unroll
  for (int i = 0; i < 3; ++i)
    for (int o = 32; o >= 1; o >>= 1) s[i] += __shfl_down(s[i], o);
  if ((tid & 63) == 0)
#pragma unroll
    for (int i = 0; i < 3; ++i) red[i][tid >> 6] = s[i];
  __syncthreads();
  if (tid < 3) {
    const float t = red[tid][0] + red[tid][1] + red[tid][2] + red[tid][3];
    out[b * 3 + tid] = t * 0.03125f;
  }
}

extern "C" void kernel_launch(void* const* d_in, const int* in_sizes, int n_in,
                              void* d_out, int out_size, void* d_ws, size_t ws_size,
                              hipStream_t stream) {
  const float* x    = (const float*)d_in[0];
  const float* w1   = (const float*)d_in[1];
  const float* W    = (const float*)d_in[2];
  const float* bnw  = (const float*)d_in[3];
  const float* wout = (const float*)d_in[4];
  float* out = (float*)d_out;

  char* ws = (char*)d_ws;
  float*          var = (float*)ws;                         // 6*1024 f32 (32 KB resv)
  float*          pre = (float*)(ws + 32768);               // 3072*1024 f32 (12 MB)
  char*           ah  = ws + 12615680;                      // blocked bf16 (6 MB)
  char*           al  = ws + 18907136;                      // blocked bf16 (6 MB)
  unsigned short* wh  = (unsigned short*)(ws + 25198592);   // blocked bf16 (10 MB)
  unsigned short* wl  = (unsigned short*)(ws + 35684352);   // blocked bf16 (10 MB)

  hipMemsetAsync(var, 0, 6 * 1024 * sizeof(float), stream);
  convert_w<<<dim3(16, 16, 5), 256, 0, stream>>>(W, wh, wl);
  layer0_fused<<<dim3(4, 64), 256, 0, stream>>>(x, w1, pre, var);
  act_kernel<<<dim3(64, 8), 256, 0, stream>>>(pre, var, bnw, ah, al);
  for (int b = 0; b < 5; ++b) {
    gemm_fused<<<768, 256, 0, stream>>>(
        ah, al, (const char*)(wh + (size_t)b * PLANE), (const char*)(wl + (size_t)b * PLANE),
        pre, var + (b + 1) * 1024);
    act_kernel<<<dim3(64, 8), 256, 0, stream>>>(pre, var + (b + 1) * 1024,
                                                bnw + (size_t)(b + 1) * 4096, ah, al);
  }
  final_kernel<<<1024, 256, 0, stream>>>(ah, al, wout, out);
}